// Round 17
// baseline (518.183 us; speedup 1.0000x reference)
//
#include <hip/hip_runtime.h>
#include <hip/hip_bf16.h>

typedef __hip_bfloat16 bf16;
typedef __attribute__((ext_vector_type(8))) short short8v;   // 8 bf16 = 4 VGPR (MFMA A/B frag)
typedef __attribute__((ext_vector_type(4))) float f32x4;     // MFMA C/D frag

// Problem dims
#define NB 4
#define NC 256
#define NPIX 36864          // 192*192
#define NH 192
#define NW 192
#define SW 98               // db3 subband: (192+8-6)/2+1
#define SH 98
#define GCH 24              // gram row-chunks (8 rows each)

// db3: analysis correlation kernels (pre-flipped dec filters); synthesis G0S=DEC_LO, G1S=DEC_HI
__device__ __constant__ float cH0A[6] = {  0.33267055295095688f,  0.80689150931333875f,  0.45987750211933132f, -0.13501102001039084f, -0.085441273882241486f, 0.035226291882100656f };
__device__ __constant__ float cH1A[6] = {  0.035226291882100656f, 0.085441273882241486f, -0.13501102001039084f, -0.45987750211933132f,  0.80689150931333875f, -0.33267055295095688f };
__device__ __constant__ float cG0S[6] = {  0.035226291882100656f, -0.085441273882241486f, -0.13501102001039084f, 0.45987750211933132f,  0.80689150931333875f,  0.33267055295095688f };
__device__ __constant__ float cG1S[6] = { -0.33267055295095688f,  0.80689150931333875f, -0.45987750211933132f, -0.13501102001039084f,  0.085441273882241486f, 0.035226291882100656f };

__device__ inline unsigned short bfbits(float f) {
    bf16 h = __float2bfloat16(f);
    return *reinterpret_cast<unsigned short*>(&h);
}
__device__ inline float b2f(short s) {
    return __bfloat162float(*reinterpret_cast<const bf16*>(&s));
}

// ---------------- fully-fused wavelet query path: x -> q (+qsum), one kernel ----------------
// round-16 structure; phase 4 re-blocked 2x4 for bank-parity mixing (same fma order/output).
__global__ __launch_bounds__(256) void k_wave(const float* __restrict__ x,
                                              const float* __restrict__ w5, const float* __restrict__ w7,
                                              const float* __restrict__ w9,
                                              bf16* __restrict__ q, float* __restrict__ qsum) {
    int w0 = blockIdx.x * 64, h0 = blockIdx.y * 32;
    int bc = blockIdx.z;
    int c = bc & 255;
    int jh0 = h0 >> 1, jw0 = w0 >> 1;
    int xr0 = h0 - 6;               // global image row of s_x row 0
    int xc0 = w0 - 8;               // global image col of s_x col 0
    __shared__ __align__(16) char smem[40320];
    float (*s_x)[80]   = (float(*)[80])smem;               // [44][80]
    float (*s_c)[36]   = (float(*)[36])smem;               // [72][36] = [4*18][36]
    float (*s_lo)[40]  = (float(*)[40])(smem + 14080);     // [44][40]
    float (*s_hi)[40]  = (float(*)[40])(smem + 21120);     // [44][40]
    float (*s_lh)[36]  = (float(*)[36])(smem + 14080);     // [64][36] = [2*32][36]
    float (*s_sub)[38] = (float(*)[38])(smem + 28160);     // [80][38] = [4*20][38]
    __shared__ float s_w[4][9];
    __shared__ float red[4];
    const float* xp = x + (size_t)bc * NPIX;
    int t = threadIdx.x;
    if (t < 36) {
        int f = t / 9, k = t - f * 9;
        const float* wsel = (f <= 1) ? w5 : (f == 2 ? w7 : w9);
        s_w[f][k] = wsel[c * 9 + k];
    }
    // phase 1: stage x (44 rows x 20 float4), zero-fill OOB
    for (int e = t; e < 880; e += 256) {
        int r = e / 20, s = e - r * 20;
        int row = xr0 + r, col0 = xc0 + s * 4;
        float4 v = make_float4(0.f, 0.f, 0.f, 0.f);
        if (row >= 0 && row < NH) {
            if (col0 >= 0 && col0 + 3 < NW) {
                v = *reinterpret_cast<const float4*>(xp + (size_t)row * NW + col0);
            } else {
#pragma unroll
                for (int j = 0; j < 4; ++j) {
                    int cc = col0 + j;
                    if (cc >= 0 && cc < NW) (&v.x)[j] = xp[(size_t)row * NW + cc];
                }
            }
        }
        *reinterpret_cast<float4*>(&s_x[r][s * 4]) = v;
    }
    __syncthreads();
    // phase 2: row DWT, column-PAIR blocked; b128 window loads + b64 paired writes
    for (int e = t; e < 836; e += 256) {
        int r = e / 19, g = e - r * 19;
        float4 va = *reinterpret_cast<const float4*>(&s_x[r][4 * g]);
        float4 vb = *reinterpret_cast<const float4*>(&s_x[r][4 * g + 4]);
        float v[8] = { va.x, va.y, va.z, va.w, vb.x, vb.y, vb.z, vb.w };
        float la0 = 0.f, ha0 = 0.f, la1 = 0.f, ha1 = 0.f;
#pragma unroll
        for (int tp = 0; tp < 6; ++tp) {
            la0 = fmaf(v[tp], cH0A[tp], la0);
            ha0 = fmaf(v[tp], cH1A[tp], ha0);
            la1 = fmaf(v[tp + 2], cH0A[tp], la1);
            ha1 = fmaf(v[tp + 2], cH1A[tp], ha1);
        }
        *reinterpret_cast<float2*>(&s_lo[r][2 * g]) = make_float2(la0, la1);
        *reinterpret_cast<float2*>(&s_hi[r][2 * g]) = make_float2(ha0, ha1);
    }
    __syncthreads();
    // phase 3: col DWT, row-PAIR blocked: outputs 2rp,2rp+1 share lo/hi rows 4rp..4rp+7
    for (int e = t; e < 380; e += 256) {
        int rp = e / 38, jc = e - rp * 38;
        float lv[8], hv[8];
#pragma unroll
        for (int i = 0; i < 8; ++i) {
            lv[i] = s_lo[4 * rp + i][jc];
            hv[i] = s_hi[4 * rp + i][jc];
        }
#pragma unroll
        for (int dr = 0; dr < 2; ++dr) {
            int r = 2 * rp + dr;
            int gr = jh0 - 1 + r, gcol = jw0 - 2 + jc;
            bool inb = (gr >= 0 && gr < SH && gcol >= 0 && gcol < SW);
            float ll = 0.f, lh = 0.f, hl = 0.f, hh = 0.f;
#pragma unroll
            for (int tp = 0; tp < 6; ++tp) {
                float l = lv[2 * dr + tp], h = hv[2 * dr + tp];
                ll = fmaf(l, cH0A[tp], ll); lh = fmaf(l, cH1A[tp], lh);
                hl = fmaf(h, cH0A[tp], hl); hh = fmaf(h, cH1A[tp], hh);
            }
            s_sub[r][jc]      = inb ? ll : 0.f;
            s_sub[20 + r][jc] = inb ? lh : 0.f;
            s_sub[40 + r][jc] = inb ? hl : 0.f;
            s_sub[60 + r][jc] = inb ? hh : 0.f;
        }
    }
    __syncthreads();
    // phase 4: depthwise 3x3, 2-row x 4-col blocked: window [4][6] -> 8 outputs.
    // items = 4 planes x 9 row-pairs x 9 col-groups = 324. Output cols 34,35 are
    // computed-but-unused (phase 5 reads cols 0..33); the single OOB window col
    // (g=8, col 38) is zero-filled and only feeds discarded outputs.
    for (int e = t; e < 324; e += 256) {
        int pl = e / 81;
        int r2 = e - pl * 81;
        int rp = r2 / 9, g = r2 - rp * 9;
        const float* wp = s_w[pl];
        int rb = pl * 20 + 2 * rp;
        int cc0 = 4 * g;
        float win[4][6];
#pragma unroll
        for (int ri = 0; ri < 4; ++ri)
#pragma unroll
            for (int cw = 0; cw < 6; ++cw) {
                int col = cc0 + 1 + cw;
                win[ri][cw] = (col < 38) ? s_sub[rb + ri][col] : 0.f;
            }
        float wreg[9];
#pragma unroll
        for (int i = 0; i < 9; ++i) wreg[i] = wp[i];
#pragma unroll
        for (int dr = 0; dr < 2; ++dr)
#pragma unroll
            for (int dc = 0; dc < 4; ++dc) {
                float a = 0.f;
#pragma unroll
                for (int ky = 0; ky < 3; ++ky)
#pragma unroll
                    for (int kx = 0; kx < 3; ++kx)
                        a = fmaf(win[dr + ky][dc + kx], wreg[ky * 3 + kx], a);
                s_c[pl * 18 + 2 * rp + dr][cc0 + dc] = a;
            }
    }
    __syncthreads();
    // phase 5: col synthesis, m-PAIR blocked: outputs m,m+1 share s_c rows m..m+3
    for (int e = t; e < 544; e += 256) {
        int row = e / 34, cc = e - row * 34;   // row = which*8 + mp
        int which = row >> 3, mp = row & 7;
        int m = 2 * mp;
        float c0v[4], c1v[4];
#pragma unroll
        for (int i = 0; i < 4; ++i) {
            c0v[i] = s_c[which * 36 + m + i][cc];
            c1v[i] = s_c[which * 36 + 18 + m + i][cc];
        }
#pragma unroll
        for (int dm = 0; dm < 2; ++dm) {
            float ae = c0v[dm] * cG0S[1] + c0v[dm + 1] * cG0S[3] + c0v[dm + 2] * cG0S[5]
                     + c1v[dm] * cG1S[1] + c1v[dm + 1] * cG1S[3] + c1v[dm + 2] * cG1S[5];
            float ao = c0v[dm] * cG0S[0] + c0v[dm + 1] * cG0S[2] + c0v[dm + 2] * cG0S[4]
                     + c1v[dm] * cG1S[0] + c1v[dm + 1] * cG1S[2] + c1v[dm + 2] * cG1S[4];
            s_lh[which * 32 + 2 * (m + dm)][cc] = ae;
            s_lh[which * 32 + 2 * (m + dm) + 1][cc] = ao;
        }
    }
    __syncthreads();
    // phase 6: paired row synthesis -> q (packed 2xbf16 stores) + sum(q^2)
    float lsum = 0.f;
    bf16* qp = q + (size_t)bc * NPIX;
#pragma unroll
    for (int it = 0; it < 4; ++it) {
        int e = t + 256 * it;
        int hh = e >> 5, m = e & 31;
        float l0 = s_lh[hh][m],     h0v = s_lh[32 + hh][m];
        float l1 = s_lh[hh][m + 1], h1v = s_lh[32 + hh][m + 1];
        float l2 = s_lh[hh][m + 2], h2v = s_lh[32 + hh][m + 2];
        float ae = l0 * cG0S[1] + l1 * cG0S[3] + l2 * cG0S[5]
                 + h0v * cG1S[1] + h1v * cG1S[3] + h2v * cG1S[5];
        float ao = l0 * cG0S[0] + l1 * cG0S[2] + l2 * cG0S[4]
                 + h0v * cG1S[0] + h1v * cG1S[2] + h2v * cG1S[4];
        unsigned pack = (unsigned)bfbits(ae) | ((unsigned)bfbits(ao) << 16);
        *reinterpret_cast<unsigned*>(qp + (size_t)(h0 + hh) * NW + w0 + 2 * m) = pack;
        lsum = fmaf(ae, ae, lsum);
        lsum = fmaf(ao, ao, lsum);
    }
#pragma unroll
    for (int off = 32; off; off >>= 1) lsum += __shfl_down(lsum, off, 64);
    if ((t & 63) == 0) red[t >> 6] = lsum;
    __syncthreads();
    if (t == 0) atomicAdd(&qsum[bc], red[0] + red[1] + red[2] + red[3]);
}

// convert qkv_w (512x256 f32) -> bf16
__global__ __launch_bounds__(256) void k_cvtw(const float* __restrict__ w, bf16* __restrict__ wb) {
    int idx = blockIdx.x * 256 + threadIdx.x;
    if (idx < 512 * 256) wb[idx] = __float2bfloat16(w[idx]);
}

// ---------------- fused transpose + MFMA GEMM from raw x ----------------
// Out[b,o,n] = sum_c W[o,c] * x[b,c,n], o-tile=256 (full), n-tile=128, 512 threads.
__global__ __launch_bounds__(512) void k_gemm_x(const float* __restrict__ x, const bf16* __restrict__ Wbf,
                                                bf16* __restrict__ Out) {
    __shared__ __align__(16) short As[256 * 64];   // 32 KB
    __shared__ __align__(16) short Bs[128 * 64];   // 16 KB
    int nt = blockIdx.x, b = blockIdx.y;
    int n0 = nt * 128;
    const float* xb = x + (size_t)b * NC * NPIX;
    int t = threadIdx.x;
    int wv = t >> 6, l = t & 63;
    int wo = wv >> 1, wn = wv & 1;
    int lrow = l >> 3, cbs0 = l & 7;
    int nq = t & 31;            // n = nq*4 + j
    int cg = t >> 5;            // c0 = cg*4  (16 groups)
    int c0 = cg * 4;
    f32x4 z4 = {0.f, 0.f, 0.f, 0.f};
    f32x4 acc[4][4];
#pragma unroll
    for (int m = 0; m < 4; ++m)
#pragma unroll
        for (int nf = 0; nf < 4; ++nf) acc[m][nf] = z4;
    for (int kc = 0; kc < 256; kc += 64) {
        __syncthreads();
        // A: 256 rows x 64 c via global_load_lds (wave-uniform dest, pre-swizzled src)
#pragma unroll
        for (int i = 0; i < 4; ++i) {
            int r0 = wv * 32 + i * 8;
            int r = r0 + lrow;
            int cb = cbs0 ^ (r & 7);
            __builtin_amdgcn_global_load_lds(
                (const __attribute__((address_space(1))) void*)(Wbf + (size_t)r * NC + kc + cb * 8),
                (__attribute__((address_space(3))) void*)(As + r0 * 64), 16, 0, 0);
        }
        // B: read x f32 [c][n] coalesced, transpose+convert in regs, swizzled b64 writes
        float4 xv[4];
#pragma unroll
        for (int ci = 0; ci < 4; ++ci)
            xv[ci] = *reinterpret_cast<const float4*>(xb + (size_t)(kc + c0 + ci) * NPIX + n0 + nq * 4);
#pragma unroll
        for (int j = 0; j < 4; ++j) {
            int n = nq * 4 + j;
            ushort4 u;
            u.x = bfbits((&xv[0].x)[j]); u.y = bfbits((&xv[1].x)[j]);
            u.z = bfbits((&xv[2].x)[j]); u.w = bfbits((&xv[3].x)[j]);
            int unit = (c0 >> 3) ^ (n & 7);
            int half = (c0 >> 2) & 1;
            *reinterpret_cast<ushort4*>(Bs + n * 64 + unit * 8 + half * 4) = u;
        }
        __syncthreads();
#pragma unroll
        for (int kk = 0; kk < 2; ++kk) {
            int col8 = kk * 4 + (l >> 4);
            short8v av[4], bv[4];
#pragma unroll
            for (int m = 0; m < 4; ++m) {
                int row = wo * 64 + m * 16 + (l & 15);
                av[m] = *(const short8v*)(As + row * 64 + (col8 ^ (row & 7)) * 8);
            }
#pragma unroll
            for (int nf = 0; nf < 4; ++nf) {
                int row = wn * 64 + nf * 16 + (l & 15);
                bv[nf] = *(const short8v*)(Bs + row * 64 + (col8 ^ (row & 7)) * 8);
            }
#pragma unroll
            for (int m = 0; m < 4; ++m)
#pragma unroll
                for (int nf = 0; nf < 4; ++nf)
                    acc[m][nf] = __builtin_amdgcn_mfma_f32_16x16x32_bf16(av[m], bv[nf], acc[m][nf], 0, 0, 0);
        }
    }
    bf16* ob = Out + (size_t)b * NC * NPIX;
#pragma unroll
    for (int m = 0; m < 4; ++m)
#pragma unroll
        for (int nf = 0; nf < 4; ++nf)
#pragma unroll
            for (int r = 0; r < 4; ++r) {
                int oo = wo * 64 + m * 16 + (l >> 4) * 4 + r;
                int nn = n0 + wn * 64 + nf * 16 + (l & 15);
                ob[(size_t)oo * NPIX + nn] = __float2bfloat16(acc[m][nf][r]);
            }
}

// ---------------- MFMA GEMM (bf16 [n][k] input): final out = wf @ v2T ----------------
template <typename TOUT>
__global__ __launch_bounds__(256) void k_gemm_bf(const bf16* __restrict__ X, const bf16* __restrict__ Wm,
                                                 int wStride, TOUT* __restrict__ Out) {
    __shared__ __align__(16) short As[128 * 64];
    __shared__ __align__(16) short Bs[128 * 64];
    int nt = blockIdx.x, ot = blockIdx.y, b = blockIdx.z;
    int n0 = nt * 128, o0 = ot * 128;
    const bf16* xb = X + (size_t)b * NPIX * NC;
    const bf16* Wb = Wm + (size_t)b * wStride;
    int t = threadIdx.x;
    int wv = t >> 6, l = t & 63;
    int wr = wv >> 1, wc = wv & 1;
    int lrow = l >> 3, cbs0 = l & 7;
    f32x4 z4 = {0.f, 0.f, 0.f, 0.f};
    f32x4 acc[4][4];
#pragma unroll
    for (int m = 0; m < 4; ++m)
#pragma unroll
        for (int nf = 0; nf < 4; ++nf) acc[m][nf] = z4;
    for (int kc = 0; kc < 256; kc += 64) {
        __syncthreads();
#pragma unroll
        for (int i = 0; i < 4; ++i) {
            int r0 = wv * 32 + i * 8;
            int r = r0 + lrow;
            int cb = cbs0 ^ (r & 7);
            __builtin_amdgcn_global_load_lds(
                (const __attribute__((address_space(1))) void*)(Wb + (size_t)(o0 + r) * NC + kc + cb * 8),
                (__attribute__((address_space(3))) void*)(As + r0 * 64), 16, 0, 0);
            __builtin_amdgcn_global_load_lds(
                (const __attribute__((address_space(1))) void*)(xb + (size_t)(n0 + r) * NC + kc + cb * 8),
                (__attribute__((address_space(3))) void*)(Bs + r0 * 64), 16, 0, 0);
        }
        __syncthreads();
#pragma unroll
        for (int kk = 0; kk < 2; ++kk) {
            int col8 = kk * 4 + (l >> 4);
            short8v av[4], bv[4];
#pragma unroll
            for (int m = 0; m < 4; ++m) {
                int row = wr * 64 + m * 16 + (l & 15);
                av[m] = *(const short8v*)(As + row * 64 + (col8 ^ (row & 7)) * 8);
            }
#pragma unroll
            for (int nf = 0; nf < 4; ++nf) {
                int row = wc * 64 + nf * 16 + (l & 15);
                bv[nf] = *(const short8v*)(Bs + row * 64 + (col8 ^ (row & 7)) * 8);
            }
#pragma unroll
            for (int m = 0; m < 4; ++m)
#pragma unroll
                for (int nf = 0; nf < 4; ++nf)
                    acc[m][nf] = __builtin_amdgcn_mfma_f32_16x16x32_bf16(av[m], bv[nf], acc[m][nf], 0, 0, 0);
        }
    }
    TOUT* ob = Out + (size_t)b * NC * NPIX;
#pragma unroll
    for (int m = 0; m < 4; ++m)
#pragma unroll
        for (int nf = 0; nf < 4; ++nf)
#pragma unroll
            for (int r = 0; r < 4; ++r) {
                int oo = o0 + wr * 64 + m * 16 + (l >> 4) * 4 + r;
                int nn = n0 + wc * 64 + nf * 16 + (l & 15);
                if constexpr (sizeof(TOUT) == 2)
                    ob[(size_t)oo * NPIX + nn] = __float2bfloat16(acc[m][nf][r]);
                else
                    ob[(size_t)oo * NPIX + nn] = acc[m][nf][r];
            }
}

// ---------------- Gram + fused dw3x3, register-direct ----------------
__device__ inline short8v dw8(const bf16* __restrict__ chan, int r, int cb,
                              const float* __restrict__ w, float& ks) {
    float v[3][10];
#pragma unroll
    for (int ri = 0; ri < 3; ++ri) {
        int r2 = r + ri - 1;
        if (r2 < 0 || r2 >= NH) {
#pragma unroll
            for (int j = 0; j < 10; ++j) v[ri][j] = 0.f;
        } else {
            const bf16* p = chan + (size_t)r2 * NW + cb;
            short8v m = *(const short8v*)p;
            v[ri][0] = (cb > 0) ? __bfloat162float(p[-1]) : 0.f;
#pragma unroll
            for (int j = 0; j < 8; ++j) v[ri][j + 1] = b2f(m[j]);
            v[ri][9] = (cb < 184) ? __bfloat162float(p[8]) : 0.f;
        }
    }
    short8v out;
#pragma unroll
    for (int j = 0; j < 8; ++j) {
        float a = 0.f;
#pragma unroll
        for (int ri = 0; ri < 3; ++ri) {
            a = fmaf(v[ri][j],     w[ri * 3 + 0], a);
            a = fmaf(v[ri][j + 1], w[ri * 3 + 1], a);
            a = fmaf(v[ri][j + 2], w[ri * 3 + 2], a);
        }
        ks = fmaf(a, a, ks);
        out[j] = (short)bfbits(a);
    }
    return out;
}

__global__ __launch_bounds__(256) void k_gram_dw(const bf16* __restrict__ qbf, const bf16* __restrict__ kraw,
                                                 const float* __restrict__ dwW,
                                                 float* __restrict__ gpart, float* __restrict__ ksum) {
    int chunk = blockIdx.x;
    int bh = blockIdx.y; int b = bh >> 3, h = bh & 7;
    const bf16* qb = qbf + ((size_t)b * NC + h * 32) * NPIX;
    const bf16* kb = kraw + ((size_t)b * NC + h * 32) * NPIX;
    __shared__ float sg[4][1024];
    __shared__ float ksh[32];
    int t = threadIdx.x;
    int wv = t >> 6, l = t & 63;
    int dlo = l & 15, kslot = l >> 4;
    float wA[9], wB[9];
#pragma unroll
    for (int i = 0; i < 9; ++i) {
        wA[i] = dwW[(h * 32 + dlo) * 9 + i];
        wB[i] = dwW[(h * 32 + dlo + 16) * 9 + i];
    }
    const bf16* q0 = qb + (size_t)dlo * NPIX;
    const bf16* q1 = qb + (size_t)(dlo + 16) * NPIX;
    const bf16* k0 = kb + (size_t)dlo * NPIX;
    const bf16* k1 = kb + (size_t)(dlo + 16) * NPIX;
    f32x4 z4 = {0.f, 0.f, 0.f, 0.f};
    f32x4 a00 = z4, a01 = z4, a10 = z4, a11 = z4;
    float ks0 = 0.f, ks1 = 0.f;
    int r0 = chunk * 8 + wv * 2;
#pragma unroll
    for (int rr = 0; rr < 2; ++rr) {
        int r = r0 + rr;
#pragma unroll
        for (int c0 = 0; c0 < 192; c0 += 32) {
            int cb = c0 + kslot * 8;
            short8v av0 = *(const short8v*)(q0 + (size_t)r * NW + cb);
            short8v av1 = *(const short8v*)(q1 + (size_t)r * NW + cb);
            short8v bv0 = dw8(k0, r, cb, wA, ks0);
            short8v bv1 = dw8(k1, r, cb, wB, ks1);
            a00 = __builtin_amdgcn_mfma_f32_16x16x32_bf16(av0, bv0, a00, 0, 0, 0);
            a01 = __builtin_amdgcn_mfma_f32_16x16x32_bf16(av0, bv1, a01, 0, 0, 0);
            a10 = __builtin_amdgcn_mfma_f32_16x16x32_bf16(av1, bv0, a10, 0, 0, 0);
            a11 = __builtin_amdgcn_mfma_f32_16x16x32_bf16(av1, bv1, a11, 0, 0, 0);
        }
    }
    if (t < 32) ksh[t] = 0.f;
#pragma unroll
    for (int j = 0; j < 4; ++j) {
        int dA = kslot * 4 + j, dB = 16 + kslot * 4 + j;
        sg[wv][dA * 32 + dlo]      = a00[j];
        sg[wv][dA * 32 + 16 + dlo] = a01[j];
        sg[wv][dB * 32 + dlo]      = a10[j];
        sg[wv][dB * 32 + 16 + dlo] = a11[j];
    }
    __syncthreads();
    float* gp = gpart + ((size_t)bh * GCH + chunk) * 1024;
#pragma unroll
    for (int i = 0; i < 4; ++i) {
        int e = t + 256 * i;
        gp[e] = sg[0][e] + sg[1][e] + sg[2][e] + sg[3][e];
    }
    atomicAdd(&ksh[dlo], ks0);
    atomicAdd(&ksh[dlo + 16], ks1);
    __syncthreads();
    if (t < 32) atomicAdd(&ksum[b * NC + h * 32 + t], ksh[t]);
}

// reduce partials + normalize + temperature + row softmax
__global__ __launch_bounds__(1024) void k_attn(const float* __restrict__ gpart, const float* __restrict__ qsum,
                                               const float* __restrict__ ksum, const float* __restrict__ temp,
                                               float* __restrict__ attn) {
    int bh = blockIdx.x;
    int b = bh >> 3, h = bh & 7;
    int t = threadIdx.x;
    int d = t >> 5, e = t & 31;
    float s = 0.f;
    for (int i = 0; i < GCH; ++i) s += gpart[((size_t)bh * GCH + i) * 1024 + t];
    float rq = 1.f / fmaxf(sqrtf(qsum[b * NC + h * 32 + d]), 1e-12f);
    float rk = 1.f / fmaxf(sqrtf(ksum[b * NC + h * 32 + e]), 1e-12f);
    s *= rq * rk * temp[h];
    float m = s;
#pragma unroll
    for (int off = 16; off; off >>= 1) m = fmaxf(m, __shfl_xor(m, off, 32));
    float ex = expf(s - m);
    float sum = ex;
#pragma unroll
    for (int off = 16; off; off >>= 1) sum += __shfl_xor(sum, off, 32);
    attn[(size_t)bh * 1024 + t] = ex / sum;
}

// fold proj into attn -> bf16
__global__ __launch_bounds__(256) void k_wfold(const float* __restrict__ proj, const float* __restrict__ attn,
                                               bf16* __restrict__ wfbf) {
    int o = blockIdx.x, b = blockIdx.y;
    int t = threadIdx.x;
    int h = t >> 5, e = t & 31;
    const float* ap = attn + (size_t)(b * 8 + h) * 1024 + e;
    const float* pp = proj + o * NC + h * 32;
    float acc = 0.f;
#pragma unroll
    for (int d = 0; d < 32; ++d) acc = fmaf(pp[d], ap[d * 32], acc);
    wfbf[((size_t)b * NC + o) * NC + t] = __float2bfloat16(acc);
}

// ---------------- dw3x3(vraw) + transpose -> v2T [b][n][e] bf16 ----------------
__global__ __launch_bounds__(256) void k_dwv(const bf16* __restrict__ vraw, const float* __restrict__ dwW,
                                             bf16* __restrict__ v2T) {
    int r = blockIdx.x;
    int cg = blockIdx.y;
    int b = blockIdx.z;
    __shared__ short s_v[3][32][204];     // cols 0..199 = global -4..195
    const bf16* vb = vraw + ((size_t)b * NC + cg * 32) * NPIX;
    int t = threadIdx.x;
    for (int idx = t; idx < 4800; idx += 256) {
        int ri = idx / 1600;
        int rem = idx - ri * 1600;
        int e = rem / 50, j = rem - e * 50;
        int gr = r + ri - 1;
        int gc0 = -4 + 4 * j;
        ushort4 u = make_ushort4(0, 0, 0, 0);
        if (gr >= 0 && gr < NH && gc0 >= 0 && gc0 + 3 < NW)
            u = *reinterpret_cast<const ushort4*>(vb + (size_t)e * NPIX + (size_t)gr * NW + gc0);
        *reinterpret_cast<ushort4*>(&s_v[ri][e][4 * j]) = u;
    }
    int e = t & 31;
    int wslot = t >> 5;
    float w9[9];
#pragma unroll
    for (int i = 0; i < 9; ++i) w9[i] = dwW[(256 + cg * 32 + e) * 9 + i];
    __syncthreads();
    bf16* ob = v2T + ((size_t)b * NPIX + (size_t)r * NW) * NC + cg * 32 + e;
#pragma unroll
    for (int wi = 0; wi < 24; ++wi) {
        int w = wslot + 8 * wi;
        int cbase = w + 3;
        float a = 0.f;
#pragma unroll
        for (int ri = 0; ri < 3; ++ri) {
            a = fmaf(b2f(s_v[ri][e][cbase]),     w9[ri * 3 + 0], a);
            a = fmaf(b2f(s_v[ri][e][cbase + 1]), w9[ri * 3 + 1], a);
            a = fmaf(b2f(s_v[ri][e][cbase + 2]), w9[ri * 3 + 2], a);
        }
        ob[(size_t)w * NC] = __float2bfloat16(a);
    }
}

// ---------------- launcher ----------------

extern "C" void kernel_launch(void* const* d_in, const int* in_sizes, int n_in,
                              void* d_out, int out_size, void* d_ws, size_t ws_size,
                              hipStream_t stream) {
    (void)in_sizes; (void)n_in; (void)out_size;
    const float* x      = (const float*)d_in[0];
    const float* qkv_w  = (const float*)d_in[1];
    const float* qkv_cw = (const float*)d_in[2];
    const float* w5     = (const float*)d_in[3];
    const float* w7     = (const float*)d_in[4];
    const float* w9     = (const float*)d_in[5];
    const float* projw  = (const float*)d_in[6];
    const float* temp   = (const float*)d_in[7];

    // WS: [0:78.7M] kraw -> (dead) -> v2T ; [78.7M:] smalls
    const size_t OFF_SM    = 78675968;
    const size_t OFF_WBF   = OFF_SM;                    // 262,144
    const size_t OFF_QSUM  = OFF_SM + 262144;           // 4,096
    const size_t OFF_KSUM  = OFF_QSUM + 4096;           // 4,096
    const size_t OFF_GPART = OFF_KSUM + 4096;           // 3,145,728 (GCH=24)
    const size_t OFF_ATTN  = OFF_GPART + 3145728;       // 131,072
    const size_t OFF_WF    = OFF_ATTN + 131072;         // 524,288
    const size_t WS_NEED   = OFF_WF + 524288;           // 82,747,392
    if (ws_size < WS_NEED) return;

    char* ws = (char*)d_ws;
    bf16*  kraw  = (bf16*)ws;
    bf16*  v2T   = (bf16*)ws;
    bf16*  wbf   = (bf16*)(ws + OFF_WBF);
    float* qsum  = (float*)(ws + OFF_QSUM);
    float* ksum  = (float*)(ws + OFF_KSUM);
    float* gpart = (float*)(ws + OFF_GPART);
    float* attn  = (float*)(ws + OFF_ATTN);
    bf16*  wfbf  = (bf16*)(ws + OFF_WF);

    // OUT: qbf [75.5M:151M]; qbf dead after gram -> vraw there; final out overwrites all.
    bf16*  qbf  = (bf16*)((char*)d_out + 75497472);
    bf16*  vraw = (bf16*)((char*)d_out + 75497472);
    float* out  = (float*)d_out;

    hipMemsetAsync(ws + OFF_QSUM, 0, 8192, stream);   // qsum + ksum

    // wavelet query path: single fused kernel x -> qbf + qsum
    k_wave<<<dim3(3, 6, NB * NC), 256, 0, stream>>>(x, w5, w7, w9, qbf, qsum);

    // weight convert
    k_cvtw<<<512, 256, 0, stream>>>(qkv_w, wbf);

    // k path: fused transpose+GEMM from raw x -> kraw, then dw+Gram
    k_gemm_x<<<dim3(288, NB), 512, 0, stream>>>(x, wbf, kraw);
    k_gram_dw<<<dim3(GCH, 32), 256, 0, stream>>>(qbf, kraw, qkv_cw, gpart, ksum);

    k_attn<<<32, 1024, 0, stream>>>(gpart, qsum, ksum, temp, attn);
    k_wfold<<<dim3(256, NB), 256, 0, stream>>>(projw, attn, wfbf);

    // v path: fused transpose+GEMM -> vraw (over dead qbf), dw+transpose -> v2T, final GEMM
    k_gemm_x<<<dim3(288, NB), 512, 0, stream>>>(x, wbf + 256 * 256, vraw);
    k_dwv<<<dim3(NH, 8, NB), 256, 0, stream>>>(vraw, qkv_cw, v2T);
    k_gemm_bf<float><<<dim3(288, 2, NB), 256, 0, stream>>>(v2T, wfbf, 65536, out);
}

// Round 18
// 511.805 us; speedup vs baseline: 1.0125x; 1.0125x over previous
//
#include <hip/hip_runtime.h>
#include <hip/hip_bf16.h>

typedef __hip_bfloat16 bf16;
typedef __attribute__((ext_vector_type(8))) short short8v;   // 8 bf16 = 4 VGPR (MFMA A/B frag)
typedef __attribute__((ext_vector_type(4))) float f32x4;     // MFMA C/D frag

// Problem dims
#define NB 4
#define NC 256
#define NPIX 36864          // 192*192
#define NH 192
#define NW 192
#define SW 98               // db3 subband: (192+8-6)/2+1
#define SH 98
#define GCH 24              // gram row-chunks (8 rows each)

// db3: analysis correlation kernels (pre-flipped dec filters); synthesis G0S=DEC_LO, G1S=DEC_HI
__device__ __constant__ float cH0A[6] = {  0.33267055295095688f,  0.80689150931333875f,  0.45987750211933132f, -0.13501102001039084f, -0.085441273882241486f, 0.035226291882100656f };
__device__ __constant__ float cH1A[6] = {  0.035226291882100656f, 0.085441273882241486f, -0.13501102001039084f, -0.45987750211933132f,  0.80689150931333875f, -0.33267055295095688f };
__device__ __constant__ float cG0S[6] = {  0.035226291882100656f, -0.085441273882241486f, -0.13501102001039084f, 0.45987750211933132f,  0.80689150931333875f,  0.33267055295095688f };
__device__ __constant__ float cG1S[6] = { -0.33267055295095688f,  0.80689150931333875f, -0.45987750211933132f, -0.13501102001039084f,  0.085441273882241486f, 0.035226291882100656f };

__device__ inline unsigned short bfbits(float f) {
    bf16 h = __float2bfloat16(f);
    return *reinterpret_cast<unsigned short*>(&h);
}
__device__ inline float b2f(short s) {
    return __bfloat162float(*reinterpret_cast<const bf16*>(&s));
}

// ---------------- fully-fused wavelet query path: x -> q (+qsum), one kernel ----------------
// round-16 structure (phase 4 = 2x2 blocked), s_sub padded to stride 39 (odd) to break
// bank-parity alignment on phase-3 writes / phase-4 reads. Bit-identical arithmetic.
__global__ __launch_bounds__(256) void k_wave(const float* __restrict__ x,
                                              const float* __restrict__ w5, const float* __restrict__ w7,
                                              const float* __restrict__ w9,
                                              bf16* __restrict__ q, float* __restrict__ qsum) {
    int w0 = blockIdx.x * 64, h0 = blockIdx.y * 32;
    int bc = blockIdx.z;
    int c = bc & 255;
    int jh0 = h0 >> 1, jw0 = w0 >> 1;
    int xr0 = h0 - 6;               // global image row of s_x row 0
    int xc0 = w0 - 8;               // global image col of s_x col 0
    __shared__ __align__(16) char smem[40640];
    float (*s_x)[80]   = (float(*)[80])smem;               // [44][80]
    float (*s_c)[36]   = (float(*)[36])smem;               // [72][36] = [4*18][36]
    float (*s_lo)[40]  = (float(*)[40])(smem + 14080);     // [44][40]
    float (*s_hi)[40]  = (float(*)[40])(smem + 21120);     // [44][40]
    float (*s_lh)[36]  = (float(*)[36])(smem + 14080);     // [64][36] = [2*32][36]
    float (*s_sub)[39] = (float(*)[39])(smem + 28160);     // [80][39] = [4*20][39], odd stride
    __shared__ float s_w[4][9];
    __shared__ float red[4];
    const float* xp = x + (size_t)bc * NPIX;
    int t = threadIdx.x;
    if (t < 36) {
        int f = t / 9, k = t - f * 9;
        const float* wsel = (f <= 1) ? w5 : (f == 2 ? w7 : w9);
        s_w[f][k] = wsel[c * 9 + k];
    }
    // phase 1: stage x (44 rows x 20 float4), zero-fill OOB
    for (int e = t; e < 880; e += 256) {
        int r = e / 20, s = e - r * 20;
        int row = xr0 + r, col0 = xc0 + s * 4;
        float4 v = make_float4(0.f, 0.f, 0.f, 0.f);
        if (row >= 0 && row < NH) {
            if (col0 >= 0 && col0 + 3 < NW) {
                v = *reinterpret_cast<const float4*>(xp + (size_t)row * NW + col0);
            } else {
#pragma unroll
                for (int j = 0; j < 4; ++j) {
                    int cc = col0 + j;
                    if (cc >= 0 && cc < NW) (&v.x)[j] = xp[(size_t)row * NW + cc];
                }
            }
        }
        *reinterpret_cast<float4*>(&s_x[r][s * 4]) = v;
    }
    __syncthreads();
    // phase 2: row DWT, column-PAIR blocked; b128 window loads + b64 paired writes
    for (int e = t; e < 836; e += 256) {
        int r = e / 19, g = e - r * 19;
        float4 va = *reinterpret_cast<const float4*>(&s_x[r][4 * g]);
        float4 vb = *reinterpret_cast<const float4*>(&s_x[r][4 * g + 4]);
        float v[8] = { va.x, va.y, va.z, va.w, vb.x, vb.y, vb.z, vb.w };
        float la0 = 0.f, ha0 = 0.f, la1 = 0.f, ha1 = 0.f;
#pragma unroll
        for (int tp = 0; tp < 6; ++tp) {
            la0 = fmaf(v[tp], cH0A[tp], la0);
            ha0 = fmaf(v[tp], cH1A[tp], ha0);
            la1 = fmaf(v[tp + 2], cH0A[tp], la1);
            ha1 = fmaf(v[tp + 2], cH1A[tp], ha1);
        }
        *reinterpret_cast<float2*>(&s_lo[r][2 * g]) = make_float2(la0, la1);
        *reinterpret_cast<float2*>(&s_hi[r][2 * g]) = make_float2(ha0, ha1);
    }
    __syncthreads();
    // phase 3: col DWT, row-PAIR blocked: outputs 2rp,2rp+1 share lo/hi rows 4rp..4rp+7
    for (int e = t; e < 380; e += 256) {
        int rp = e / 38, jc = e - rp * 38;
        float lv[8], hv[8];
#pragma unroll
        for (int i = 0; i < 8; ++i) {
            lv[i] = s_lo[4 * rp + i][jc];
            hv[i] = s_hi[4 * rp + i][jc];
        }
#pragma unroll
        for (int dr = 0; dr < 2; ++dr) {
            int r = 2 * rp + dr;
            int gr = jh0 - 1 + r, gcol = jw0 - 2 + jc;
            bool inb = (gr >= 0 && gr < SH && gcol >= 0 && gcol < SW);
            float ll = 0.f, lh = 0.f, hl = 0.f, hh = 0.f;
#pragma unroll
            for (int tp = 0; tp < 6; ++tp) {
                float l = lv[2 * dr + tp], h = hv[2 * dr + tp];
                ll = fmaf(l, cH0A[tp], ll); lh = fmaf(l, cH1A[tp], lh);
                hl = fmaf(h, cH0A[tp], hl); hh = fmaf(h, cH1A[tp], hh);
            }
            s_sub[r][jc]      = inb ? ll : 0.f;
            s_sub[20 + r][jc] = inb ? lh : 0.f;
            s_sub[40 + r][jc] = inb ? hl : 0.f;
            s_sub[60 + r][jc] = inb ? hh : 0.f;
        }
    }
    __syncthreads();
    // phase 4: depthwise 3x3, 2x2-blocked (4 outputs share a 4x4 window)
    for (int e = t; e < 612; e += 256) {
        int pl = e / 153;
        int r2 = e - pl * 153;
        int rp = r2 / 17, gp4 = r2 - rp * 17;
        const float* wp = s_w[pl];
        int rb = pl * 20 + 2 * rp;
        int cc = 2 * gp4;
        float win[4][4];
#pragma unroll
        for (int ri = 0; ri < 4; ++ri)
#pragma unroll
            for (int cj = 0; cj < 4; ++cj)
                win[ri][cj] = s_sub[rb + ri][cc + 1 + cj];
        float wreg[9];
#pragma unroll
        for (int i = 0; i < 9; ++i) wreg[i] = wp[i];
#pragma unroll
        for (int dr = 0; dr < 2; ++dr)
#pragma unroll
            for (int dc = 0; dc < 2; ++dc) {
                float a = 0.f;
#pragma unroll
                for (int ky = 0; ky < 3; ++ky)
#pragma unroll
                    for (int kx = 0; kx < 3; ++kx)
                        a = fmaf(win[dr + ky][dc + kx], wreg[ky * 3 + kx], a);
                s_c[pl * 18 + 2 * rp + dr][cc + dc] = a;
            }
    }
    __syncthreads();
    // phase 5: col synthesis, m-PAIR blocked: outputs m,m+1 share s_c rows m..m+3
    for (int e = t; e < 544; e += 256) {
        int row = e / 34, cc = e - row * 34;   // row = which*8 + mp
        int which = row >> 3, mp = row & 7;
        int m = 2 * mp;
        float c0v[4], c1v[4];
#pragma unroll
        for (int i = 0; i < 4; ++i) {
            c0v[i] = s_c[which * 36 + m + i][cc];
            c1v[i] = s_c[which * 36 + 18 + m + i][cc];
        }
#pragma unroll
        for (int dm = 0; dm < 2; ++dm) {
            float ae = c0v[dm] * cG0S[1] + c0v[dm + 1] * cG0S[3] + c0v[dm + 2] * cG0S[5]
                     + c1v[dm] * cG1S[1] + c1v[dm + 1] * cG1S[3] + c1v[dm + 2] * cG1S[5];
            float ao = c0v[dm] * cG0S[0] + c0v[dm + 1] * cG0S[2] + c0v[dm + 2] * cG0S[4]
                     + c1v[dm] * cG1S[0] + c1v[dm + 1] * cG1S[2] + c1v[dm + 2] * cG1S[4];
            s_lh[which * 32 + 2 * (m + dm)][cc] = ae;
            s_lh[which * 32 + 2 * (m + dm) + 1][cc] = ao;
        }
    }
    __syncthreads();
    // phase 6: paired row synthesis -> q (packed 2xbf16 stores) + sum(q^2)
    float lsum = 0.f;
    bf16* qp = q + (size_t)bc * NPIX;
#pragma unroll
    for (int it = 0; it < 4; ++it) {
        int e = t + 256 * it;
        int hh = e >> 5, m = e & 31;
        float l0 = s_lh[hh][m],     h0v = s_lh[32 + hh][m];
        float l1 = s_lh[hh][m + 1], h1v = s_lh[32 + hh][m + 1];
        float l2 = s_lh[hh][m + 2], h2v = s_lh[32 + hh][m + 2];
        float ae = l0 * cG0S[1] + l1 * cG0S[3] + l2 * cG0S[5]
                 + h0v * cG1S[1] + h1v * cG1S[3] + h2v * cG1S[5];
        float ao = l0 * cG0S[0] + l1 * cG0S[2] + l2 * cG0S[4]
                 + h0v * cG1S[0] + h1v * cG1S[2] + h2v * cG1S[4];
        unsigned pack = (unsigned)bfbits(ae) | ((unsigned)bfbits(ao) << 16);
        *reinterpret_cast<unsigned*>(qp + (size_t)(h0 + hh) * NW + w0 + 2 * m) = pack;
        lsum = fmaf(ae, ae, lsum);
        lsum = fmaf(ao, ao, lsum);
    }
#pragma unroll
    for (int off = 32; off; off >>= 1) lsum += __shfl_down(lsum, off, 64);
    if ((t & 63) == 0) red[t >> 6] = lsum;
    __syncthreads();
    if (t == 0) atomicAdd(&qsum[bc], red[0] + red[1] + red[2] + red[3]);
}

// convert qkv_w (512x256 f32) -> bf16
__global__ __launch_bounds__(256) void k_cvtw(const float* __restrict__ w, bf16* __restrict__ wb) {
    int idx = blockIdx.x * 256 + threadIdx.x;
    if (idx < 512 * 256) wb[idx] = __float2bfloat16(w[idx]);
}

// ---------------- fused transpose + MFMA GEMM from raw x ----------------
// Out[b,o,n] = sum_c W[o,c] * x[b,c,n], o-tile=256 (full), n-tile=128, 512 threads.
__global__ __launch_bounds__(512) void k_gemm_x(const float* __restrict__ x, const bf16* __restrict__ Wbf,
                                                bf16* __restrict__ Out) {
    __shared__ __align__(16) short As[256 * 64];   // 32 KB
    __shared__ __align__(16) short Bs[128 * 64];   // 16 KB
    int nt = blockIdx.x, b = blockIdx.y;
    int n0 = nt * 128;
    const float* xb = x + (size_t)b * NC * NPIX;
    int t = threadIdx.x;
    int wv = t >> 6, l = t & 63;
    int wo = wv >> 1, wn = wv & 1;
    int lrow = l >> 3, cbs0 = l & 7;
    int nq = t & 31;            // n = nq*4 + j
    int cg = t >> 5;            // c0 = cg*4  (16 groups)
    int c0 = cg * 4;
    f32x4 z4 = {0.f, 0.f, 0.f, 0.f};
    f32x4 acc[4][4];
#pragma unroll
    for (int m = 0; m < 4; ++m)
#pragma unroll
        for (int nf = 0; nf < 4; ++nf) acc[m][nf] = z4;
    for (int kc = 0; kc < 256; kc += 64) {
        __syncthreads();
        // A: 256 rows x 64 c via global_load_lds (wave-uniform dest, pre-swizzled src)
#pragma unroll
        for (int i = 0; i < 4; ++i) {
            int r0 = wv * 32 + i * 8;
            int r = r0 + lrow;
            int cb = cbs0 ^ (r & 7);
            __builtin_amdgcn_global_load_lds(
                (const __attribute__((address_space(1))) void*)(Wbf + (size_t)r * NC + kc + cb * 8),
                (__attribute__((address_space(3))) void*)(As + r0 * 64), 16, 0, 0);
        }
        // B: read x f32 [c][n] coalesced, transpose+convert in regs, swizzled b64 writes
        float4 xv[4];
#pragma unroll
        for (int ci = 0; ci < 4; ++ci)
            xv[ci] = *reinterpret_cast<const float4*>(xb + (size_t)(kc + c0 + ci) * NPIX + n0 + nq * 4);
#pragma unroll
        for (int j = 0; j < 4; ++j) {
            int n = nq * 4 + j;
            ushort4 u;
            u.x = bfbits((&xv[0].x)[j]); u.y = bfbits((&xv[1].x)[j]);
            u.z = bfbits((&xv[2].x)[j]); u.w = bfbits((&xv[3].x)[j]);
            int unit = (c0 >> 3) ^ (n & 7);
            int half = (c0 >> 2) & 1;
            *reinterpret_cast<ushort4*>(Bs + n * 64 + unit * 8 + half * 4) = u;
        }
        __syncthreads();
#pragma unroll
        for (int kk = 0; kk < 2; ++kk) {
            int col8 = kk * 4 + (l >> 4);
            short8v av[4], bv[4];
#pragma unroll
            for (int m = 0; m < 4; ++m) {
                int row = wo * 64 + m * 16 + (l & 15);
                av[m] = *(const short8v*)(As + row * 64 + (col8 ^ (row & 7)) * 8);
            }
#pragma unroll
            for (int nf = 0; nf < 4; ++nf) {
                int row = wn * 64 + nf * 16 + (l & 15);
                bv[nf] = *(const short8v*)(Bs + row * 64 + (col8 ^ (row & 7)) * 8);
            }
#pragma unroll
            for (int m = 0; m < 4; ++m)
#pragma unroll
                for (int nf = 0; nf < 4; ++nf)
                    acc[m][nf] = __builtin_amdgcn_mfma_f32_16x16x32_bf16(av[m], bv[nf], acc[m][nf], 0, 0, 0);
        }
    }
    bf16* ob = Out + (size_t)b * NC * NPIX;
#pragma unroll
    for (int m = 0; m < 4; ++m)
#pragma unroll
        for (int nf = 0; nf < 4; ++nf)
#pragma unroll
            for (int r = 0; r < 4; ++r) {
                int oo = wo * 64 + m * 16 + (l >> 4) * 4 + r;
                int nn = n0 + wn * 64 + nf * 16 + (l & 15);
                ob[(size_t)oo * NPIX + nn] = __float2bfloat16(acc[m][nf][r]);
            }
}

// ---------------- MFMA GEMM (bf16 [n][k] input): final out = wf @ v2T ----------------
template <typename TOUT>
__global__ __launch_bounds__(256) void k_gemm_bf(const bf16* __restrict__ X, const bf16* __restrict__ Wm,
                                                 int wStride, TOUT* __restrict__ Out) {
    __shared__ __align__(16) short As[128 * 64];
    __shared__ __align__(16) short Bs[128 * 64];
    int nt = blockIdx.x, ot = blockIdx.y, b = blockIdx.z;
    int n0 = nt * 128, o0 = ot * 128;
    const bf16* xb = X + (size_t)b * NPIX * NC;
    const bf16* Wb = Wm + (size_t)b * wStride;
    int t = threadIdx.x;
    int wv = t >> 6, l = t & 63;
    int wr = wv >> 1, wc = wv & 1;
    int lrow = l >> 3, cbs0 = l & 7;
    f32x4 z4 = {0.f, 0.f, 0.f, 0.f};
    f32x4 acc[4][4];
#pragma unroll
    for (int m = 0; m < 4; ++m)
#pragma unroll
        for (int nf = 0; nf < 4; ++nf) acc[m][nf] = z4;
    for (int kc = 0; kc < 256; kc += 64) {
        __syncthreads();
#pragma unroll
        for (int i = 0; i < 4; ++i) {
            int r0 = wv * 32 + i * 8;
            int r = r0 + lrow;
            int cb = cbs0 ^ (r & 7);
            __builtin_amdgcn_global_load_lds(
                (const __attribute__((address_space(1))) void*)(Wb + (size_t)(o0 + r) * NC + kc + cb * 8),
                (__attribute__((address_space(3))) void*)(As + r0 * 64), 16, 0, 0);
            __builtin_amdgcn_global_load_lds(
                (const __attribute__((address_space(1))) void*)(xb + (size_t)(n0 + r) * NC + kc + cb * 8),
                (__attribute__((address_space(3))) void*)(Bs + r0 * 64), 16, 0, 0);
        }
        __syncthreads();
#pragma unroll
        for (int kk = 0; kk < 2; ++kk) {
            int col8 = kk * 4 + (l >> 4);
            short8v av[4], bv[4];
#pragma unroll
            for (int m = 0; m < 4; ++m) {
                int row = wr * 64 + m * 16 + (l & 15);
                av[m] = *(const short8v*)(As + row * 64 + (col8 ^ (row & 7)) * 8);
            }
#pragma unroll
            for (int nf = 0; nf < 4; ++nf) {
                int row = wc * 64 + nf * 16 + (l & 15);
                bv[nf] = *(const short8v*)(Bs + row * 64 + (col8 ^ (row & 7)) * 8);
            }
#pragma unroll
            for (int m = 0; m < 4; ++m)
#pragma unroll
                for (int nf = 0; nf < 4; ++nf)
                    acc[m][nf] = __builtin_amdgcn_mfma_f32_16x16x32_bf16(av[m], bv[nf], acc[m][nf], 0, 0, 0);
        }
    }
    TOUT* ob = Out + (size_t)b * NC * NPIX;
#pragma unroll
    for (int m = 0; m < 4; ++m)
#pragma unroll
        for (int nf = 0; nf < 4; ++nf)
#pragma unroll
            for (int r = 0; r < 4; ++r) {
                int oo = o0 + wr * 64 + m * 16 + (l >> 4) * 4 + r;
                int nn = n0 + wc * 64 + nf * 16 + (l & 15);
                if constexpr (sizeof(TOUT) == 2)
                    ob[(size_t)oo * NPIX + nn] = __float2bfloat16(acc[m][nf][r]);
                else
                    ob[(size_t)oo * NPIX + nn] = acc[m][nf][r];
            }
}

// ---------------- Gram + fused dw3x3, register-direct ----------------
__device__ inline short8v dw8(const bf16* __restrict__ chan, int r, int cb,
                              const float* __restrict__ w, float& ks) {
    float v[3][10];
#pragma unroll
    for (int ri = 0; ri < 3; ++ri) {
        int r2 = r + ri - 1;
        if (r2 < 0 || r2 >= NH) {
#pragma unroll
            for (int j = 0; j < 10; ++j) v[ri][j] = 0.f;
        } else {
            const bf16* p = chan + (size_t)r2 * NW + cb;
            short8v m = *(const short8v*)p;
            v[ri][0] = (cb > 0) ? __bfloat162float(p[-1]) : 0.f;
#pragma unroll
            for (int j = 0; j < 8; ++j) v[ri][j + 1] = b2f(m[j]);
            v[ri][9] = (cb < 184) ? __bfloat162float(p[8]) : 0.f;
        }
    }
    short8v out;
#pragma unroll
    for (int j = 0; j < 8; ++j) {
        float a = 0.f;
#pragma unroll
        for (int ri = 0; ri < 3; ++ri) {
            a = fmaf(v[ri][j],     w[ri * 3 + 0], a);
            a = fmaf(v[ri][j + 1], w[ri * 3 + 1], a);
            a = fmaf(v[ri][j + 2], w[ri * 3 + 2], a);
        }
        ks = fmaf(a, a, ks);
        out[j] = (short)bfbits(a);
    }
    return out;
}

__global__ __launch_bounds__(256) void k_gram_dw(const bf16* __restrict__ qbf, const bf16* __restrict__ kraw,
                                                 const float* __restrict__ dwW,
                                                 float* __restrict__ gpart, float* __restrict__ ksum) {
    int chunk = blockIdx.x;
    int bh = blockIdx.y; int b = bh >> 3, h = bh & 7;
    const bf16* qb = qbf + ((size_t)b * NC + h * 32) * NPIX;
    const bf16* kb = kraw + ((size_t)b * NC + h * 32) * NPIX;
    __shared__ float sg[4][1024];
    __shared__ float ksh[32];
    int t = threadIdx.x;
    int wv = t >> 6, l = t & 63;
    int dlo = l & 15, kslot = l >> 4;
    float wA[9], wB[9];
#pragma unroll
    for (int i = 0; i < 9; ++i) {
        wA[i] = dwW[(h * 32 + dlo) * 9 + i];
        wB[i] = dwW[(h * 32 + dlo + 16) * 9 + i];
    }
    const bf16* q0 = qb + (size_t)dlo * NPIX;
    const bf16* q1 = qb + (size_t)(dlo + 16) * NPIX;
    const bf16* k0 = kb + (size_t)dlo * NPIX;
    const bf16* k1 = kb + (size_t)(dlo + 16) * NPIX;
    f32x4 z4 = {0.f, 0.f, 0.f, 0.f};
    f32x4 a00 = z4, a01 = z4, a10 = z4, a11 = z4;
    float ks0 = 0.f, ks1 = 0.f;
    int r0 = chunk * 8 + wv * 2;
#pragma unroll
    for (int rr = 0; rr < 2; ++rr) {
        int r = r0 + rr;
#pragma unroll
        for (int c0 = 0; c0 < 192; c0 += 32) {
            int cb = c0 + kslot * 8;
            short8v av0 = *(const short8v*)(q0 + (size_t)r * NW + cb);
            short8v av1 = *(const short8v*)(q1 + (size_t)r * NW + cb);
            short8v bv0 = dw8(k0, r, cb, wA, ks0);
            short8v bv1 = dw8(k1, r, cb, wB, ks1);
            a00 = __builtin_amdgcn_mfma_f32_16x16x32_bf16(av0, bv0, a00, 0, 0, 0);
            a01 = __builtin_amdgcn_mfma_f32_16x16x32_bf16(av0, bv1, a01, 0, 0, 0);
            a10 = __builtin_amdgcn_mfma_f32_16x16x32_bf16(av1, bv0, a10, 0, 0, 0);
            a11 = __builtin_amdgcn_mfma_f32_16x16x32_bf16(av1, bv1, a11, 0, 0, 0);
        }
    }
    if (t < 32) ksh[t] = 0.f;
#pragma unroll
    for (int j = 0; j < 4; ++j) {
        int dA = kslot * 4 + j, dB = 16 + kslot * 4 + j;
        sg[wv][dA * 32 + dlo]      = a00[j];
        sg[wv][dA * 32 + 16 + dlo] = a01[j];
        sg[wv][dB * 32 + dlo]      = a10[j];
        sg[wv][dB * 32 + 16 + dlo] = a11[j];
    }
    __syncthreads();
    float* gp = gpart + ((size_t)bh * GCH + chunk) * 1024;
#pragma unroll
    for (int i = 0; i < 4; ++i) {
        int e = t + 256 * i;
        gp[e] = sg[0][e] + sg[1][e] + sg[2][e] + sg[3][e];
    }
    atomicAdd(&ksh[dlo], ks0);
    atomicAdd(&ksh[dlo + 16], ks1);
    __syncthreads();
    if (t < 32) atomicAdd(&ksum[b * NC + h * 32 + t], ksh[t]);
}

// reduce partials + normalize + temperature + row softmax
__global__ __launch_bounds__(1024) void k_attn(const float* __restrict__ gpart, const float* __restrict__ qsum,
                                               const float* __restrict__ ksum, const float* __restrict__ temp,
                                               float* __restrict__ attn) {
    int bh = blockIdx.x;
    int b = bh >> 3, h = bh & 7;
    int t = threadIdx.x;
    int d = t >> 5, e = t & 31;
    float s = 0.f;
    for (int i = 0; i < GCH; ++i) s += gpart[((size_t)bh * GCH + i) * 1024 + t];
    float rq = 1.f / fmaxf(sqrtf(qsum[b * NC + h * 32 + d]), 1e-12f);
    float rk = 1.f / fmaxf(sqrtf(ksum[b * NC + h * 32 + e]), 1e-12f);
    s *= rq * rk * temp[h];
    float m = s;
#pragma unroll
    for (int off = 16; off; off >>= 1) m = fmaxf(m, __shfl_xor(m, off, 32));
    float ex = expf(s - m);
    float sum = ex;
#pragma unroll
    for (int off = 16; off; off >>= 1) sum += __shfl_xor(sum, off, 32);
    attn[(size_t)bh * 1024 + t] = ex / sum;
}

// fold proj into attn -> bf16
__global__ __launch_bounds__(256) void k_wfold(const float* __restrict__ proj, const float* __restrict__ attn,
                                               bf16* __restrict__ wfbf) {
    int o = blockIdx.x, b = blockIdx.y;
    int t = threadIdx.x;
    int h = t >> 5, e = t & 31;
    const float* ap = attn + (size_t)(b * 8 + h) * 1024 + e;
    const float* pp = proj + o * NC + h * 32;
    float acc = 0.f;
#pragma unroll
    for (int d = 0; d < 32; ++d) acc = fmaf(pp[d], ap[d * 32], acc);
    wfbf[((size_t)b * NC + o) * NC + t] = __float2bfloat16(acc);
}

// ---------------- dw3x3(vraw) + transpose -> v2T [b][n][e] bf16 ----------------
__global__ __launch_bounds__(256) void k_dwv(const bf16* __restrict__ vraw, const float* __restrict__ dwW,
                                             bf16* __restrict__ v2T) {
    int r = blockIdx.x;
    int cg = blockIdx.y;
    int b = blockIdx.z;
    __shared__ short s_v[3][32][204];     // cols 0..199 = global -4..195
    const bf16* vb = vraw + ((size_t)b * NC + cg * 32) * NPIX;
    int t = threadIdx.x;
    for (int idx = t; idx < 4800; idx += 256) {
        int ri = idx / 1600;
        int rem = idx - ri * 1600;
        int e = rem / 50, j = rem - e * 50;
        int gr = r + ri - 1;
        int gc0 = -4 + 4 * j;
        ushort4 u = make_ushort4(0, 0, 0, 0);
        if (gr >= 0 && gr < NH && gc0 >= 0 && gc0 + 3 < NW)
            u = *reinterpret_cast<const ushort4*>(vb + (size_t)e * NPIX + (size_t)gr * NW + gc0);
        *reinterpret_cast<ushort4*>(&s_v[ri][e][4 * j]) = u;
    }
    int e = t & 31;
    int wslot = t >> 5;
    float w9[9];
#pragma unroll
    for (int i = 0; i < 9; ++i) w9[i] = dwW[(256 + cg * 32 + e) * 9 + i];
    __syncthreads();
    bf16* ob = v2T + ((size_t)b * NPIX + (size_t)r * NW) * NC + cg * 32 + e;
#pragma unroll
    for (int wi = 0; wi < 24; ++wi) {
        int w = wslot + 8 * wi;
        int cbase = w + 3;
        float a = 0.f;
#pragma unroll
        for (int ri = 0; ri < 3; ++ri) {
            a = fmaf(b2f(s_v[ri][e][cbase]),     w9[ri * 3 + 0], a);
            a = fmaf(b2f(s_v[ri][e][cbase + 1]), w9[ri * 3 + 1], a);
            a = fmaf(b2f(s_v[ri][e][cbase + 2]), w9[ri * 3 + 2], a);
        }
        ob[(size_t)w * NC] = __float2bfloat16(a);
    }
}

// ---------------- launcher ----------------

extern "C" void kernel_launch(void* const* d_in, const int* in_sizes, int n_in,
                              void* d_out, int out_size, void* d_ws, size_t ws_size,
                              hipStream_t stream) {
    (void)in_sizes; (void)n_in; (void)out_size;
    const float* x      = (const float*)d_in[0];
    const float* qkv_w  = (const float*)d_in[1];
    const float* qkv_cw = (const float*)d_in[2];
    const float* w5     = (const float*)d_in[3];
    const float* w7     = (const float*)d_in[4];
    const float* w9     = (const float*)d_in[5];
    const float* projw  = (const float*)d_in[6];
    const float* temp   = (const float*)d_in[7];

    // WS: [0:78.7M] kraw -> (dead) -> v2T ; [78.7M:] smalls
    const size_t OFF_SM    = 78675968;
    const size_t OFF_WBF   = OFF_SM;                    // 262,144
    const size_t OFF_QSUM  = OFF_SM + 262144;           // 4,096
    const size_t OFF_KSUM  = OFF_QSUM + 4096;           // 4,096
    const size_t OFF_GPART = OFF_KSUM + 4096;           // 3,145,728 (GCH=24)
    const size_t OFF_ATTN  = OFF_GPART + 3145728;       // 131,072
    const size_t OFF_WF    = OFF_ATTN + 131072;         // 524,288
    const size_t WS_NEED   = OFF_WF + 524288;           // 82,747,392
    if (ws_size < WS_NEED) return;

    char* ws = (char*)d_ws;
    bf16*  kraw  = (bf16*)ws;
    bf16*  v2T   = (bf16*)ws;
    bf16*  wbf   = (bf16*)(ws + OFF_WBF);
    float* qsum  = (float*)(ws + OFF_QSUM);
    float* ksum  = (float*)(ws + OFF_KSUM);
    float* gpart = (float*)(ws + OFF_GPART);
    float* attn  = (float*)(ws + OFF_ATTN);
    bf16*  wfbf  = (bf16*)(ws + OFF_WF);

    // OUT: qbf [75.5M:151M]; qbf dead after gram -> vraw there; final out overwrites all.
    bf16*  qbf  = (bf16*)((char*)d_out + 75497472);
    bf16*  vraw = (bf16*)((char*)d_out + 75497472);
    float* out  = (float*)d_out;

    hipMemsetAsync(ws + OFF_QSUM, 0, 8192, stream);   // qsum + ksum

    // wavelet query path: single fused kernel x -> qbf + qsum
    k_wave<<<dim3(3, 6, NB * NC), 256, 0, stream>>>(x, w5, w7, w9, qbf, qsum);

    // weight convert
    k_cvtw<<<512, 256, 0, stream>>>(qkv_w, wbf);

    // k path: fused transpose+GEMM from raw x -> kraw, then dw+Gram
    k_gemm_x<<<dim3(288, NB), 512, 0, stream>>>(x, wbf, kraw);
    k_gram_dw<<<dim3(GCH, 32), 256, 0, stream>>>(qbf, kraw, qkv_cw, gpart, ksum);

    k_attn<<<32, 1024, 0, stream>>>(gpart, qsum, ksum, temp, attn);
    k_wfold<<<dim3(256, NB), 256, 0, stream>>>(projw, attn, wfbf);

    // v path: fused transpose+GEMM -> vraw (over dead qbf), dw+transpose -> v2T, final GEMM
    k_gemm_x<<<dim3(288, NB), 512, 0, stream>>>(x, wbf + 256 * 256, vraw);
    k_dwv<<<dim3(NH, 8, NB), 256, 0, stream>>>(vraw, qkv_cw, v2T);
    k_gemm_bf<float><<<dim3(288, 2, NB), 256, 0, stream>>>(v2T, wfbf, 65536, out);
}